// Round 9
// baseline (57.146 us; speedup 1.0000x reference)
//
#include <hip/hip_runtime.h>
#include <hip/hip_bf16.h>

#define EPS 1e-6f

typedef __attribute__((ext_vector_type(4))) float f32x4;

// pack 4 floats into 4 fp8-e4m3 bytes (k-order: x->byte0 .. w->byte3)
__device__ inline unsigned int pack_fp8x4(float x, float y, float z, float w) {
  int r = 0;
  r = __builtin_amdgcn_cvt_pk_fp8_f32(x, y, r, false);  // bytes 0,1
  r = __builtin_amdgcn_cvt_pk_fp8_f32(z, w, r, true);   // bytes 2,3
  return (unsigned int)r;
}

// ---------------------------------------------------------------------------
// Kernel A: per-speaker precompute (192 threads, float4-vectorized).
// Writes: a8[i][d] = fp8e4m3(dvec[i][d]/||dvec_i||)      (10240 x 768, 7.9 MB)
//         c8[n][d] = fp8e4m3(ctrd[n][d]/||ctrd_n||)      (1024 x 768)
//         simown[i] = fp32 cosine(dvec_i, excl-centroid) (10240, exact fp32)
// Also zeroes rowsum[10240] and out[0].   (verified rounds 6-8)
// ---------------------------------------------------------------------------
__global__ void __launch_bounds__(192) ge2e_pre(
    const float* __restrict__ dv, unsigned int* __restrict__ a8u,
    unsigned int* __restrict__ c8u, float* __restrict__ simown,
    float* __restrict__ rowsum, float* __restrict__ out) {
  const int n = blockIdx.x, t = threadIdx.x;  // t in [0,192): owns dims 4t..4t+3
  if (n == 0 && t == 0) out[0] = 0.f;  // consumed by ge2e_final (stream-ordered)
  const float* base = dv + (size_t)n * 7680;
  float4 v[10];
  float4 s4 = make_float4(0.f, 0.f, 0.f, 0.f);
#pragma unroll
  for (int m = 0; m < 10; ++m) {
    v[m] = *reinterpret_cast<const float4*>(&base[m * 768 + 4 * t]);
    s4.x += v[m].x; s4.y += v[m].y; s4.z += v[m].z; s4.w += v[m].w;
  }
  float part[21];
#pragma unroll
  for (int m = 0; m < 10; ++m) {
    part[m]      = v[m].x * s4.x + v[m].y * s4.y + v[m].z * s4.z + v[m].w * s4.w;
    part[10 + m] = v[m].x * v[m].x + v[m].y * v[m].y + v[m].z * v[m].z + v[m].w * v[m].w;
  }
  part[20] = s4.x * s4.x + s4.y * s4.y + s4.z * s4.z + s4.w * s4.w;
#pragma unroll
  for (int k = 0; k < 21; ++k) {
#pragma unroll
    for (int off = 32; off >= 1; off >>= 1) part[k] += __shfl_xor(part[k], off);
  }
  __shared__ float red[3][21];
  __shared__ float bc[21];
  const int lane = t & 63, wid = t >> 6;
  if (lane == 0) {
#pragma unroll
    for (int k = 0; k < 21; ++k) red[wid][k] = part[k];
  }
  __syncthreads();
  if (t < 21) bc[t] = red[0][t] + red[1][t] + red[2][t];
  __syncthreads();
  const float ss = bc[20];
  // centroid = sums/10; cnorm = max(|ctrd|,eps) -> normalize sums by max(|sums|,10eps)
  const float rc = 1.0f / fmaxf(sqrtf(ss), 10.0f * EPS);
  c8u[n * 192 + t] = pack_fp8x4(s4.x * rc, s4.y * rc, s4.z * rc, s4.w * rc);
#pragma unroll
  for (int m = 0; m < 10; ++m) {
    float rd = 1.0f / fmaxf(sqrtf(bc[10 + m]), EPS);
    a8u[(size_t)(n * 10 + m) * 192 + t] =
        pack_fp8x4(v[m].x * rd, v[m].y * rd, v[m].z * rd, v[m].w * rd);
  }
  if (t < 10) {
    float dot = bc[t], sq = bc[10 + t];
    float dn = fmaxf(sqrtf(sq), EPS);
    float en = fmaxf(sqrtf(fmaxf(ss - 2.f * dot + sq, 0.f)) * (1.0f / 9.0f), EPS);
    simown[n * 10 + t] = ((dot - sq) * (1.0f / 9.0f)) / (dn * en);
    rowsum[n * 10 + t] = 0.f;  // accumulated by ge2e_gemm atomics
  }
}

// ---------------------------------------------------------------------------
// Kernel B: fp8 MFMA GEMM (10240x1024x768), 256x256 tile, 8 waves (2Mx4N),
// phase-split schedule with COUNTED vmcnt (T3+T4 port):
//   * K-tile BK=64, double-buffered; staging unit = K-HALF half-tile
//     (256 rows x 32B = 8 KB = 1 global_load_lds/thread) so every phase's
//     data needs are wave-uniform -> static counted waits work.
//   * 4 phases per K-tile: (row-quad rq, k-half kh). Per phase: 1 half-tile
//     stage of K-tile t+1 (order A_k0,B_k0,A_k1,B_k1), 8 ds_read_b64,
//     setprio-wrapped 16 MFMA. Waits: vmcnt(2)+barrier at phases 0 and 2
//     ONLY (each load gets 3-4 phases of flight; never drain to 0 in-loop).
//   * 16B-slot XOR swizzle (k16 ^= (row>>2)&1) on BOTH stage source and
//     ds_read -> wave64 b64 reads hit each bank exactly 4x4B = minimum.
// Grid 160 blocks (40x4) x 512 thr = 1 block/CU, all co-resident, no tail.
// Bijective XCD swizzle (160 = 8 x 20): each XCD holds 5 A-panels + all B
// (~1.8 MB) in its L2. Epilogue: diagonal replace + exp-sum atomics (r5).
// ---------------------------------------------------------------------------
__global__ void __launch_bounds__(512) ge2e_gemm(
    const unsigned char* __restrict__ a8, const unsigned char* __restrict__ c8,
    const float* __restrict__ simown, const float* __restrict__ wp,
    float* __restrict__ rowsum) {
  __shared__ __align__(16) unsigned char As[2][2][8192];  // [buf][khalf][256*32]
  __shared__ __align__(16) unsigned char Bs[2][2][8192];
  const int t = threadIdx.x;
  const int lane = t & 63, wid = t >> 6;
  const int bx = blockIdx.x;
  const int wg = (bx & 7) * 20 + (bx >> 3);  // bijective XCD swizzle, 160=8x20
  const int rb = wg >> 2, cb = wg & 3;
  const int row0 = rb * 256, col0 = cb * 256;
  const int wm = wid >> 2, wn = wid & 3;     // wave tile: 128 rows x 64 cols
  const int l15 = lane & 15, lg = lane >> 4;

  f32x4 acc[8][4];
#pragma unroll
  for (int i = 0; i < 8; ++i)
#pragma unroll
    for (int j = 0; j < 4; ++j) acc[i][j] = (f32x4){0.f, 0.f, 0.f, 0.f};

  // staging geometry: thread covers chunk = 16B; half-tile = 512 chunks.
  // chunk c -> row c>>1, LDS 16B-slot c&1; global k16 fetched = (c&1)^((row>>2)&1)
  // (inverse-swizzled source; LDS dest stays linear -- rule #21).
  const int chunk = wid * 64 + lane;
  const int srow = chunk >> 1;
  const int sk16 = (chunk & 1) ^ ((srow >> 2) & 1);
  const unsigned char* aS = a8 + (size_t)(row0 + srow) * 768 + sk16 * 16;
  const unsigned char* bS = c8 + (size_t)(col0 + srow) * 768 + sk16 * 16;

  auto stageA = [&](int buf, int kh, int kb) {
    __builtin_amdgcn_global_load_lds(
        (const __attribute__((address_space(1))) unsigned int*)(aS + kb + kh * 32),
        (__attribute__((address_space(3))) unsigned int*)&As[buf][kh][wid * 1024],
        16, 0, 0);
  };
  auto stageB = [&](int buf, int kh, int kb) {
    __builtin_amdgcn_global_load_lds(
        (const __attribute__((address_space(1))) unsigned int*)(bS + kb + kh * 32),
        (__attribute__((address_space(3))) unsigned int*)&Bs[buf][kh][wid * 1024],
        16, 0, 0);
  };
  // frag read: 8 fp8 at global k8 = lg (within the 32B k-half window);
  // swizzled slot = (lg>>1) ^ ((row>>2)&1), sub-offset (lg&1)*8.
  auto ldA = [&](int buf, int kh, int fr) -> long long {
    const int r = wm * 128 + fr * 16 + l15;
    return *(const long long*)&As[buf][kh]
        [r * 32 + ((((lg >> 1) ^ ((r >> 2) & 1)) << 4) | ((lg & 1) << 3))];
  };
  auto ldB = [&](int buf, int kh, int fc) -> long long {
    const int c = wn * 64 + fc * 16 + l15;
    return *(const long long*)&Bs[buf][kh]
        [c * 32 + ((((lg >> 1) ^ ((c >> 2) & 1)) << 4) | ((lg & 1) << 3))];
  };

#define MFMA_Q(RQ, AF, BF)                                                    \
  do {                                                                        \
    __builtin_amdgcn_s_setprio(1);                                            \
    _Pragma("unroll") for (int i_ = 0; i_ < 4; ++i_)                          \
    _Pragma("unroll") for (int j_ = 0; j_ < 4; ++j_)                          \
      acc[(RQ) * 4 + i_][j_] = __builtin_amdgcn_mfma_f32_16x16x32_fp8_fp8(    \
          AF[i_], BF[j_], acc[(RQ) * 4 + i_][j_], 0, 0, 0);                   \
    __builtin_amdgcn_s_setprio(0);                                            \
  } while (0)

#define SYNC2 asm volatile("s_waitcnt vmcnt(2)" ::: "memory"); __builtin_amdgcn_s_barrier();
#define SYNC0 asm volatile("s_waitcnt vmcnt(0)" ::: "memory"); __builtin_amdgcn_s_barrier();

  // prologue: K-tile 0's four half-tiles into buf 0 (4 outstanding)
  stageA(0, 0, 0); stageB(0, 0, 0); stageA(0, 1, 0); stageB(0, 1, 0);

  long long af[4], bf[4];
  for (int tt = 0; tt < 11; ++tt) {   // K-tiles 0..10 (stage t+1)
    const int b = tt & 1, nb = b ^ 1;
    const int kn = (tt + 1) * 64;
    // phase 0: (rq0, kh0)
    SYNC2                      // A_k0(t),B_k0(t) landed for all waves
    stageA(nb, 0, kn);
#pragma unroll
    for (int j = 0; j < 4; ++j) bf[j] = ldB(b, 0, j);
#pragma unroll
    for (int i = 0; i < 4; ++i) af[i] = ldA(b, 0, i);
    MFMA_Q(0, af, bf);
    // phase 1: (rq1, kh0) -- B kh0 frags reused
    stageB(nb, 0, kn);
#pragma unroll
    for (int i = 0; i < 4; ++i) af[i] = ldA(b, 0, 4 + i);
    MFMA_Q(1, af, bf);
    // phase 2: (rq0, kh1)
    SYNC2                      // A_k1(t),B_k1(t) landed
    stageA(nb, 1, kn);
#pragma unroll
    for (int j = 0; j < 4; ++j) bf[j] = ldB(b, 1, j);
#pragma unroll
    for (int i = 0; i < 4; ++i) af[i] = ldA(b, 1, i);
    MFMA_Q(0, af, bf);
    // phase 3: (rq1, kh1)
    stageB(nb, 1, kn);
#pragma unroll
    for (int i = 0; i < 4; ++i) af[i] = ldA(b, 1, 4 + i);
    MFMA_Q(1, af, bf);
  }
  // peeled K-tile 11 (buf 1, no stages; epilogue waits)
  {
    SYNC2
#pragma unroll
    for (int j = 0; j < 4; ++j) bf[j] = ldB(1, 0, j);
#pragma unroll
    for (int i = 0; i < 4; ++i) af[i] = ldA(1, 0, i);
    MFMA_Q(0, af, bf);
#pragma unroll
    for (int i = 0; i < 4; ++i) af[i] = ldA(1, 0, 4 + i);
    MFMA_Q(1, af, bf);
    SYNC0                      // only 2 outstanding remain -> full drain once
#pragma unroll
    for (int j = 0; j < 4; ++j) bf[j] = ldB(1, 1, j);
#pragma unroll
    for (int i = 0; i < 4; ++i) af[i] = ldA(1, 1, i);
    MFMA_Q(0, af, bf);
#pragma unroll
    for (int i = 0; i < 4; ++i) af[i] = ldA(1, 1, 4 + i);
    MFMA_Q(1, af, bf);
  }
#undef MFMA_Q
#undef SYNC2
#undef SYNC0

  // Epilogue: vv = w*cos (diagonal: fp32 sim_own); rowsum[grow] += sum_j exp(vv)
  // |vv| <= ~10.1 -> exp fp32-safe without max subtraction; bias b cancels.
  const float wv = wp[0];
  const int R0 = row0 + wm * 128, C0 = col0 + wn * 64;
#pragma unroll
  for (int i = 0; i < 8; ++i) {
#pragma unroll
    for (int r = 0; r < 4; ++r) {
      const int grow = R0 + i * 16 + lg * 4 + r;
      const int ownc = grow / 10;  // own speaker column
      float sm = 0.f;
#pragma unroll
      for (int j = 0; j < 4; ++j) {
        const int gcol = C0 + j * 16 + l15;
        float vv = wv * acc[i][j][r];
        if (gcol == ownc) vv = wv * simown[grow];
        sm += __expf(vv);
      }
#pragma unroll
      for (int off = 1; off < 16; off <<= 1) sm += __shfl_xor(sm, off, 16);
      if (l15 == 0) atomicAdd(&rowsum[grow], sm);
    }
  }
}

// ---------------------------------------------------------------------------
// Kernel C: loss_i = log(rowsum_i) - w*simown_i; sum over 10240 into d_out.
// ---------------------------------------------------------------------------
__global__ void __launch_bounds__(256) ge2e_final(
    const float* __restrict__ rowsum, const float* __restrict__ simown,
    const float* __restrict__ wp, float* __restrict__ out) {
  const int i = blockIdx.x * 256 + threadIdx.x;  // 0..10239
  const float wv = wp[0];
  float loss = logf(rowsum[i]) - wv * simown[i];
#pragma unroll
  for (int off = 32; off >= 1; off >>= 1) loss += __shfl_xor(loss, off);
  __shared__ float red[4];
  const int lane = threadIdx.x & 63, wid = threadIdx.x >> 6;
  if (lane == 0) red[wid] = loss;
  __syncthreads();
  if (threadIdx.x == 0) atomicAdd(out, red[0] + red[1] + red[2] + red[3]);
}

extern "C" void kernel_launch(void* const* d_in, const int* in_sizes, int n_in,
                              void* d_out, int out_size, void* d_ws, size_t ws_size,
                              hipStream_t stream) {
  (void)in_sizes; (void)n_in; (void)out_size; (void)ws_size;
  const float* dv = (const float*)d_in[0];
  const float* wp = (const float*)d_in[1];
  // d_in[2] (bias b) cancels exactly in -log_softmax[own]; unused.

  unsigned char* a8 = (unsigned char*)d_ws;                         // 7,864,320 B
  unsigned char* c8 = (unsigned char*)d_ws + 7864320;               //   786,432 B
  float* simown = (float*)((char*)d_ws + 8650752);                  //    40,960 B
  float* rowsum = (float*)((char*)d_ws + 8691712);                  //    40,960 B
  float* out = (float*)d_out;

  ge2e_pre<<<1024, 192, 0, stream>>>(dv, (unsigned int*)a8, (unsigned int*)c8,
                                     simown, rowsum, out);
  ge2e_gemm<<<160, 512, 0, stream>>>(a8, c8, simown, wp, rowsum);
  ge2e_final<<<40, 256, 0, stream>>>(rowsum, simown, wp, out);
}

// Round 10
// 43.956 us; speedup vs baseline: 1.3001x; 1.3001x over previous
//
#include <hip/hip_runtime.h>
#include <hip/hip_bf16.h>

#define EPS 1e-6f

typedef __attribute__((ext_vector_type(4))) float f32x4;

// pack 4 floats into 4 fp8-e4m3 bytes (k-order: x->byte0 .. w->byte3)
__device__ inline unsigned int pack_fp8x4(float x, float y, float z, float w) {
  int r = 0;
  r = __builtin_amdgcn_cvt_pk_fp8_f32(x, y, r, false);  // bytes 0,1
  r = __builtin_amdgcn_cvt_pk_fp8_f32(z, w, r, true);   // bytes 2,3
  return (unsigned int)r;
}

// ---------------------------------------------------------------------------
// Kernel A: per-speaker precompute (192 threads, float4-vectorized).
// Writes: a8[i][d] = fp8e4m3(dvec[i][d]/||dvec_i||)      (10240 x 768, 7.9 MB)
//         c8[n][d] = fp8e4m3(ctrd[n][d]/||ctrd_n||)      (1024 x 768)
//         simown[i] = fp32 cosine(dvec_i, excl-centroid) (10240, exact fp32)
// Also zeroes rowsum[10240] and out[0].   (verified rounds 6-9)
// ---------------------------------------------------------------------------
__global__ void __launch_bounds__(192) ge2e_pre(
    const float* __restrict__ dv, unsigned int* __restrict__ a8u,
    unsigned int* __restrict__ c8u, float* __restrict__ simown,
    float* __restrict__ rowsum, float* __restrict__ out) {
  const int n = blockIdx.x, t = threadIdx.x;  // t in [0,192): owns dims 4t..4t+3
  if (n == 0 && t == 0) out[0] = 0.f;  // consumed by ge2e_final (stream-ordered)
  const float* base = dv + (size_t)n * 7680;
  float4 v[10];
  float4 s4 = make_float4(0.f, 0.f, 0.f, 0.f);
#pragma unroll
  for (int m = 0; m < 10; ++m) {
    v[m] = *reinterpret_cast<const float4*>(&base[m * 768 + 4 * t]);
    s4.x += v[m].x; s4.y += v[m].y; s4.z += v[m].z; s4.w += v[m].w;
  }
  float part[21];
#pragma unroll
  for (int m = 0; m < 10; ++m) {
    part[m]      = v[m].x * s4.x + v[m].y * s4.y + v[m].z * s4.z + v[m].w * s4.w;
    part[10 + m] = v[m].x * v[m].x + v[m].y * v[m].y + v[m].z * v[m].z + v[m].w * v[m].w;
  }
  part[20] = s4.x * s4.x + s4.y * s4.y + s4.z * s4.z + s4.w * s4.w;
#pragma unroll
  for (int k = 0; k < 21; ++k) {
#pragma unroll
    for (int off = 32; off >= 1; off >>= 1) part[k] += __shfl_xor(part[k], off);
  }
  __shared__ float red[3][21];
  __shared__ float bc[21];
  const int lane = t & 63, wid = t >> 6;
  if (lane == 0) {
#pragma unroll
    for (int k = 0; k < 21; ++k) red[wid][k] = part[k];
  }
  __syncthreads();
  if (t < 21) bc[t] = red[0][t] + red[1][t] + red[2][t];
  __syncthreads();
  const float ss = bc[20];
  // centroid = sums/10; cnorm = max(|ctrd|,eps) -> normalize sums by max(|sums|,10eps)
  const float rc = 1.0f / fmaxf(sqrtf(ss), 10.0f * EPS);
  c8u[n * 192 + t] = pack_fp8x4(s4.x * rc, s4.y * rc, s4.z * rc, s4.w * rc);
#pragma unroll
  for (int m = 0; m < 10; ++m) {
    float rd = 1.0f / fmaxf(sqrtf(bc[10 + m]), EPS);
    a8u[(size_t)(n * 10 + m) * 192 + t] =
        pack_fp8x4(v[m].x * rd, v[m].y * rd, v[m].z * rd, v[m].w * rd);
  }
  if (t < 10) {
    float dot = bc[t], sq = bc[10 + t];
    float dn = fmaxf(sqrtf(sq), EPS);
    float en = fmaxf(sqrtf(fmaxf(ss - 2.f * dot + sq, 0.f)) * (1.0f / 9.0f), EPS);
    simown[n * 10 + t] = ((dot - sq) * (1.0f / 9.0f)) / (dn * en);
    rowsum[n * 10 + t] = 0.f;  // accumulated by ge2e_gemm atomics
  }
}

// ---------------------------------------------------------------------------
// Kernel B: fp8 MFMA GEMM (10240x1024x768), tile 320x128, 8 waves (4Mx2N,
// wave = 80x64, acc[5][4] = 80 VGPR), counted-vmcnt superstep schedule:
//   * Grid 32x8 = 256 blocks = EXACTLY 1 block/CU (fixes round-9's 160/256
//     underfill). __launch_bounds__(512,2) -> VGPR cap 256 (fixes round-9's
//     spill at cap 128).
//   * Superstep = BK=128 (two K=64 MFMA tiles): staging = A 40KB + B 16KB =
//     56 x 1KB segments = EXACTLY 7 global_load_lds per wave (uniform ->
//     static counted waits valid). 6 supersteps for K=768.
//   * Per superstep: STAGE(s+1) -> vmcnt(7) (never 0 in-loop; s's loads had
//     a full superstep of flight) -> barrier -> 80 MFMA + 36 ds_read_b64
//     (setprio-wrapped) -> barrier (certifies buf[(s+1)&1] free for the
//     NEXT iteration's STAGE -- audited, no race).
//     => 2 barriers + 1 counted wait per 80 MFMA (vs 2-phase's per 16).
//   * 16B-slot XOR swizzle slot^=(row&7) on BOTH stage source and ds_read
//     (rule #21) -> <=2-way LDS conflicts (free per m136).
// LDS 112 KB dbuf. Bijective XCD swizzle (256 = 8 x 32): per-XCD working set
// A-slice 983KB + B 786KB < 4MB L2. Epilogue: diagonal replace + exp-sum
// atomics (|w*sim| <= ~10.1 -> no max pass; bias b cancels).
// ---------------------------------------------------------------------------
__global__ void __launch_bounds__(512, 2) ge2e_gemm(
    const unsigned char* __restrict__ a8, const unsigned char* __restrict__ c8,
    const float* __restrict__ simown, const float* __restrict__ wp,
    float* __restrict__ rowsum) {
  __shared__ __align__(16) unsigned char As[2][40960];  // [buf] 320 rows x 128B
  __shared__ __align__(16) unsigned char Bs[2][16384];  // [buf] 128 rows x 128B
  const int t = threadIdx.x;
  const int lane = t & 63, wid = t >> 6;
  const int bx = blockIdx.x;
  const int wg = (bx & 7) * 32 + (bx >> 3);  // bijective XCD swizzle, 256=8x32
  const int rb = wg >> 3, cb = wg & 7;
  const int row0 = rb * 320, col0 = cb * 128;
  const int wm = wid >> 1, wn = wid & 1;     // wave tile: 80 rows x 64 cols
  const int l15 = lane & 15, lg = lane >> 4;
  const int l8 = lane >> 3, sl = lane & 7;
  const int sk16 = sl ^ l8;                  // inverse-swizzled source 16B slot

  f32x4 acc[5][4];
#pragma unroll
  for (int i = 0; i < 5; ++i)
#pragma unroll
    for (int j = 0; j < 4; ++j) acc[i][j] = (f32x4){0.f, 0.f, 0.f, 0.f};

  // Stage superstep ks (K-bytes [ks*128, ks*128+128)) into buf.
  // 56 segments of 1KB (64 lanes x 16B); segment g: rows g*8..g*8+7,
  // 8 chunks/row; LDS slot (lane&7) of row g*8+(lane>>3) holds global
  // k16 = slot ^ (row&7) = (lane&7)^(lane>>3)  [XOR-8 involution].
  auto STAGE = [&](int buf, int ks) {
#pragma unroll
    for (int j = 0; j < 7; ++j) {
      const int g = wid * 7 + j;  // 0..55 (wave-uniform)
      if (g < 40) {
        const unsigned char* src =
            a8 + (size_t)(row0 + g * 8 + l8) * 768 + ks * 128 + sk16 * 16;
        __builtin_amdgcn_global_load_lds(
            (const __attribute__((address_space(1))) unsigned int*)src,
            (__attribute__((address_space(3))) unsigned int*)&As[buf][g * 1024],
            16, 0, 0);
      } else {
        const unsigned char* src =
            c8 + (size_t)(col0 + (g - 40) * 8 + l8) * 768 + ks * 128 + sk16 * 16;
        __builtin_amdgcn_global_load_lds(
            (const __attribute__((address_space(1))) unsigned int*)src,
            (__attribute__((address_space(3))) unsigned int*)&Bs[buf][(g - 40) * 1024],
            16, 0, 0);
      }
    }
  };

  // frag read: 8 fp8 k-elems for (kt, kh) at swizzled slot, b64.
  auto ldA = [&](int buf, int kt, int kh, int fr) -> long long {
    const int row = wm * 80 + fr * 16 + l15;
    const int k16 = (kt * 4 + kh * 2 + (lg >> 1)) ^ (row & 7);
    return *(const long long*)&As[buf][row * 128 + k16 * 16 + (lg & 1) * 8];
  };
  auto ldB = [&](int buf, int kt, int kh, int fc) -> long long {
    const int row = wn * 64 + fc * 16 + l15;
    const int k16 = (kt * 4 + kh * 2 + (lg >> 1)) ^ (row & 7);
    return *(const long long*)&Bs[buf][row * 128 + k16 * 16 + (lg & 1) * 8];
  };

  auto COMPUTE = [&](int buf) {
#pragma unroll
    for (int kt = 0; kt < 2; ++kt) {  // two K=64 MFMA tiles per superstep
      long long af[5][2], bf[4][2];
#pragma unroll
      for (int fc = 0; fc < 4; ++fc)
#pragma unroll
        for (int kh = 0; kh < 2; ++kh) bf[fc][kh] = ldB(buf, kt, kh, fc);
#pragma unroll
      for (int fr = 0; fr < 5; ++fr)
#pragma unroll
        for (int kh = 0; kh < 2; ++kh) af[fr][kh] = ldA(buf, kt, kh, fr);
      __builtin_amdgcn_s_setprio(1);
#pragma unroll
      for (int kh = 0; kh < 2; ++kh)
#pragma unroll
        for (int fr = 0; fr < 5; ++fr)
#pragma unroll
          for (int fc = 0; fc < 4; ++fc)
            acc[fr][fc] = __builtin_amdgcn_mfma_f32_16x16x32_fp8_fp8(
                af[fr][kh], bf[fc][kh], acc[fr][fc], 0, 0, 0);
      __builtin_amdgcn_s_setprio(0);
    }
  };

  // prologue: superstep 0's 7 loads (flight exposed once)
  STAGE(0, 0);
#pragma unroll
  for (int s = 0; s < 6; ++s) {
    if (s < 5) {
      STAGE((s + 1) & 1, s + 1);  // buf free: certified by iter s-1's trailing barrier
      asm volatile("s_waitcnt vmcnt(7)" ::: "memory");  // s's 7 landed, s+1 in flight
    } else {
      asm volatile("s_waitcnt vmcnt(0)" ::: "memory");  // only s=5's 7 remain
    }
    __builtin_amdgcn_s_barrier();
    COMPUTE(s & 1);
    if (s < 5) __builtin_amdgcn_s_barrier();  // all waves done reading buf[s&1]
  }

  // Epilogue: vv = w*cos (diagonal: fp32 sim_own); rowsum[grow] += sum_j exp(vv)
  // |vv| <= ~10.1 -> exp fp32-safe without max subtraction; bias b cancels.
  const float wv = wp[0];
  const int R0 = row0 + wm * 80, C0 = col0 + wn * 64;
#pragma unroll
  for (int fr = 0; fr < 5; ++fr) {
#pragma unroll
    for (int r = 0; r < 4; ++r) {
      const int grow = R0 + fr * 16 + lg * 4 + r;
      const int ownc = grow / 10;  // own speaker column
      float sm = 0.f;
#pragma unroll
      for (int fc = 0; fc < 4; ++fc) {
        const int gcol = C0 + fc * 16 + l15;
        float vv = wv * acc[fr][fc][r];
        if (gcol == ownc) vv = wv * simown[grow];
        sm += __expf(vv);
      }
#pragma unroll
      for (int off = 1; off < 16; off <<= 1) sm += __shfl_xor(sm, off, 16);
      if (l15 == 0) atomicAdd(&rowsum[grow], sm);
    }
  }
}

// ---------------------------------------------------------------------------
// Kernel C: loss_i = log(rowsum_i) - w*simown_i; sum over 10240 into d_out.
// ---------------------------------------------------------------------------
__global__ void __launch_bounds__(256) ge2e_final(
    const float* __restrict__ rowsum, const float* __restrict__ simown,
    const float* __restrict__ wp, float* __restrict__ out) {
  const int i = blockIdx.x * 256 + threadIdx.x;  // 0..10239
  const float wv = wp[0];
  float loss = logf(rowsum[i]) - wv * simown[i];
#pragma unroll
  for (int off = 32; off >= 1; off >>= 1) loss += __shfl_xor(loss, off);
  __shared__ float red[4];
  const int lane = threadIdx.x & 63, wid = threadIdx.x >> 6;
  if (lane == 0) red[wid] = loss;
  __syncthreads();
  if (threadIdx.x == 0) atomicAdd(out, red[0] + red[1] + red[2] + red[3]);
}

extern "C" void kernel_launch(void* const* d_in, const int* in_sizes, int n_in,
                              void* d_out, int out_size, void* d_ws, size_t ws_size,
                              hipStream_t stream) {
  (void)in_sizes; (void)n_in; (void)out_size; (void)ws_size;
  const float* dv = (const float*)d_in[0];
  const float* wp = (const float*)d_in[1];
  // d_in[2] (bias b) cancels exactly in -log_softmax[own]; unused.

  unsigned char* a8 = (unsigned char*)d_ws;                         // 7,864,320 B
  unsigned char* c8 = (unsigned char*)d_ws + 7864320;               //   786,432 B
  float* simown = (float*)((char*)d_ws + 8650752);                  //    40,960 B
  float* rowsum = (float*)((char*)d_ws + 8691712);                  //    40,960 B
  float* out = (float*)d_out;

  ge2e_pre<<<1024, 192, 0, stream>>>(dv, (unsigned int*)a8, (unsigned int*)c8,
                                     simown, rowsum, out);
  ge2e_gemm<<<256, 512, 0, stream>>>(a8, c8, simown, wp, rowsum);
  ge2e_final<<<40, 256, 0, stream>>>(rowsum, simown, wp, out);
}

// Round 11
// 43.588 us; speedup vs baseline: 1.3110x; 1.0084x over previous
//
#include <hip/hip_runtime.h>
#include <hip/hip_bf16.h>

#define EPS 1e-6f

typedef __attribute__((ext_vector_type(4))) float f32x4;

// pack 4 floats into 4 fp8-e4m3 bytes (k-order: x->byte0 .. w->byte3)
__device__ inline unsigned int pack_fp8x4(float x, float y, float z, float w) {
  int r = 0;
  r = __builtin_amdgcn_cvt_pk_fp8_f32(x, y, r, false);  // bytes 0,1
  r = __builtin_amdgcn_cvt_pk_fp8_f32(z, w, r, true);   // bytes 2,3
  return (unsigned int)r;
}

// ---------------------------------------------------------------------------
// Kernel A: per-speaker precompute (192 threads, float4-vectorized).
// Writes: a8[i][d] = fp8e4m3(dvec[i][d]/||dvec_i||)      (10240 x 768, 7.9 MB)
//         c8[n][d] = fp8e4m3(ctrd[n][d]/||ctrd_n||)      (1024 x 768)
//         simown[i] = fp32 cosine(dvec_i, excl-centroid) (10240, exact fp32)
// Also zeroes rowsum[10240] and out[0].   (verified rounds 6-10)
// ---------------------------------------------------------------------------
__global__ void __launch_bounds__(192) ge2e_pre(
    const float* __restrict__ dv, unsigned int* __restrict__ a8u,
    unsigned int* __restrict__ c8u, float* __restrict__ simown,
    float* __restrict__ rowsum, float* __restrict__ out) {
  const int n = blockIdx.x, t = threadIdx.x;  // t in [0,192): owns dims 4t..4t+3
  if (n == 0 && t == 0) out[0] = 0.f;  // consumed by ge2e_final (stream-ordered)
  const float* base = dv + (size_t)n * 7680;
  float4 v[10];
  float4 s4 = make_float4(0.f, 0.f, 0.f, 0.f);
#pragma unroll
  for (int m = 0; m < 10; ++m) {
    v[m] = *reinterpret_cast<const float4*>(&base[m * 768 + 4 * t]);
    s4.x += v[m].x; s4.y += v[m].y; s4.z += v[m].z; s4.w += v[m].w;
  }
  float part[21];
#pragma unroll
  for (int m = 0; m < 10; ++m) {
    part[m]      = v[m].x * s4.x + v[m].y * s4.y + v[m].z * s4.z + v[m].w * s4.w;
    part[10 + m] = v[m].x * v[m].x + v[m].y * v[m].y + v[m].z * v[m].z + v[m].w * v[m].w;
  }
  part[20] = s4.x * s4.x + s4.y * s4.y + s4.z * s4.z + s4.w * s4.w;
#pragma unroll
  for (int k = 0; k < 21; ++k) {
#pragma unroll
    for (int off = 32; off >= 1; off >>= 1) part[k] += __shfl_xor(part[k], off);
  }
  __shared__ float red[3][21];
  __shared__ float bc[21];
  const int lane = t & 63, wid = t >> 6;
  if (lane == 0) {
#pragma unroll
    for (int k = 0; k < 21; ++k) red[wid][k] = part[k];
  }
  __syncthreads();
  if (t < 21) bc[t] = red[0][t] + red[1][t] + red[2][t];
  __syncthreads();
  const float ss = bc[20];
  // centroid = sums/10; cnorm = max(|ctrd|,eps) -> normalize sums by max(|sums|,10eps)
  const float rc = 1.0f / fmaxf(sqrtf(ss), 10.0f * EPS);
  c8u[n * 192 + t] = pack_fp8x4(s4.x * rc, s4.y * rc, s4.z * rc, s4.w * rc);
#pragma unroll
  for (int m = 0; m < 10; ++m) {
    float rd = 1.0f / fmaxf(sqrtf(bc[10 + m]), EPS);
    a8u[(size_t)(n * 10 + m) * 192 + t] =
        pack_fp8x4(v[m].x * rd, v[m].y * rd, v[m].z * rd, v[m].w * rd);
  }
  if (t < 10) {
    float dot = bc[t], sq = bc[10 + t];
    float dn = fmaxf(sqrtf(sq), EPS);
    float en = fmaxf(sqrtf(fmaxf(ss - 2.f * dot + sq, 0.f)) * (1.0f / 9.0f), EPS);
    simown[n * 10 + t] = ((dot - sq) * (1.0f / 9.0f)) / (dn * en);
    rowsum[n * 10 + t] = 0.f;  // accumulated by ge2e_gemm atomics
  }
}

// ---------------------------------------------------------------------------
// Kernel B: fp8 MFMA GEMM (10240x1024x768), tile 320x64, 8 waves (4Mx2N,
// wave = 80x32, acc[5][2] = 40 VGPR), counted-vmcnt superstep schedule at
// TWO BLOCKS PER CU (round-10 fix: 1 block/CU left nothing to hide the
// barrier/vmcnt/ds_read stalls; co-resident block's waves now fill them):
//   * Grid 32x16 = 512 blocks = exactly 2/CU, no tail. LDS 48 KB dbuf ->
//     96 KB/CU. __launch_bounds__(512,4) caps VGPR at 128 (est ~100) ->
//     2-block residency guaranteed, no spill (acc is half of round 10's).
//   * Superstep BK=64: staging = A 320x64B (20 segs) + B 64x64B (4 segs)
//     = 24 x 1KB segments = EXACTLY 3 global_load_lds per wave (uniform).
//     12 supersteps; per superstep: STAGE(s+1) -> vmcnt(3) (tile s landed;
//     s+1 stays in flight -- never drain in-loop) -> barrier -> 14 ds_read
//     + 20 MFMA (setprio) -> barrier.
//   * 64B-row swizzle: 16B-slot ^= (row>>1)&3 on BOTH stage source and
//     ds_read (involution, rule #21) -> b64 frag reads ~2-way = free.
// Bijective XCD swizzle (512 = 8 x 64): per-XCD A-slice 983KB + B 786KB
// < 4MB L2. Epilogue: diagonal replace + exp-sum atomics (no max pass:
// |w*sim| <= ~10.1; bias b cancels in log_softmax - pick).
// ---------------------------------------------------------------------------
__global__ void __launch_bounds__(512, 4) ge2e_gemm(
    const unsigned char* __restrict__ a8, const unsigned char* __restrict__ c8,
    const float* __restrict__ simown, const float* __restrict__ wp,
    float* __restrict__ rowsum) {
  __shared__ __align__(16) unsigned char As[2][20480];  // [buf] 320 rows x 64B
  __shared__ __align__(16) unsigned char Bs[2][4096];   // [buf]  64 rows x 64B
  const int t = threadIdx.x;
  const int lane = t & 63, wid = t >> 6;
  const int bx = blockIdx.x;
  const int wg = (bx & 7) * 64 + (bx >> 3);  // bijective XCD swizzle, 512=8x64
  const int rb = wg >> 4, cb = wg & 15;
  const int row0 = rb * 320, col0 = cb * 64;
  const int wm = wid >> 1, wn = wid & 1;     // wave tile: 80 rows x 32 cols
  const int l15 = lane & 15, lg = lane >> 4;
  // staging lane geometry: seg = 16 rows x 4 chunks(16B); row = g*16+(lane>>2),
  // LDS slot = lane&3 holds global chunk slot^((row>>1)&3) = (lane&3)^((lane>>3)&3)
  const int srow = lane >> 2;
  const int sk = (lane & 3) ^ ((lane >> 3) & 3);  // inverse-swizzled src slot

  f32x4 acc[5][2];
#pragma unroll
  for (int i = 0; i < 5; ++i)
#pragma unroll
    for (int j = 0; j < 2; ++j) acc[i][j] = (f32x4){0.f, 0.f, 0.f, 0.f};

  auto STAGE = [&](int buf, int ks) {
#pragma unroll
    for (int j = 0; j < 3; ++j) {
      const int g = wid * 3 + j;  // 0..23, wave-uniform
      if (g < 20) {               // A: rows g*16..g*16+15
        const unsigned char* src =
            a8 + (size_t)(row0 + g * 16 + srow) * 768 + ks * 64 + sk * 16;
        __builtin_amdgcn_global_load_lds(
            (const __attribute__((address_space(1))) unsigned int*)src,
            (__attribute__((address_space(3))) unsigned int*)&As[buf][g * 1024],
            16, 0, 0);
      } else {                    // B: rows (g-20)*16..+15
        const unsigned char* src =
            c8 + (size_t)(col0 + (g - 20) * 16 + srow) * 768 + ks * 64 + sk * 16;
        __builtin_amdgcn_global_load_lds(
            (const __attribute__((address_space(1))) unsigned int*)src,
            (__attribute__((address_space(3))) unsigned int*)&Bs[buf][(g - 20) * 1024],
            16, 0, 0);
      }
    }
  };

  // frag read: 8 fp8 k-elems for k-half kh; swizzled 16B slot, b64-aligned.
  auto ldA = [&](int buf, int kh, int fr) -> long long {
    const int row = wm * 80 + fr * 16 + l15;
    const int slot = (kh * 2 + (lg >> 1)) ^ ((row >> 1) & 3);
    return *(const long long*)&As[buf][row * 64 + slot * 16 + (lg & 1) * 8];
  };
  auto ldB = [&](int buf, int kh, int fc) -> long long {
    const int row = wn * 32 + fc * 16 + l15;
    const int slot = (kh * 2 + (lg >> 1)) ^ ((row >> 1) & 3);
    return *(const long long*)&Bs[buf][row * 64 + slot * 16 + (lg & 1) * 8];
  };

  auto COMPUTE = [&](int buf) {
    long long af[5][2], bf[2][2];
#pragma unroll
    for (int fc = 0; fc < 2; ++fc)
#pragma unroll
      for (int kh = 0; kh < 2; ++kh) bf[fc][kh] = ldB(buf, kh, fc);
#pragma unroll
    for (int fr = 0; fr < 5; ++fr)
#pragma unroll
      for (int kh = 0; kh < 2; ++kh) af[fr][kh] = ldA(buf, kh, fr);
    __builtin_amdgcn_s_setprio(1);
#pragma unroll
    for (int kh = 0; kh < 2; ++kh)
#pragma unroll
      for (int fr = 0; fr < 5; ++fr)
#pragma unroll
        for (int fc = 0; fc < 2; ++fc)
          acc[fr][fc] = __builtin_amdgcn_mfma_f32_16x16x32_fp8_fp8(
              af[fr][kh], bf[fc][kh], acc[fr][fc], 0, 0, 0);
    __builtin_amdgcn_s_setprio(0);
  };

  // prologue: superstep 0's 3 loads
  STAGE(0, 0);
#pragma unroll
  for (int s = 0; s < 12; ++s) {
    if (s < 11) {
      STAGE((s + 1) & 1, s + 1);  // buf free per iter s-1's trailing barrier
      asm volatile("s_waitcnt vmcnt(3)" ::: "memory");  // tile s landed
    } else {
      asm volatile("s_waitcnt vmcnt(0)" ::: "memory");
    }
    __builtin_amdgcn_s_barrier();
    COMPUTE(s & 1);
    if (s < 11) __builtin_amdgcn_s_barrier();  // all waves done with buf[s&1]
  }

  // Epilogue: vv = w*cos (diagonal: fp32 sim_own); rowsum[grow] += sum_j exp(vv)
  const float wv = wp[0];
  const int R0 = row0 + wm * 80, C0 = col0 + wn * 32;
#pragma unroll
  for (int fr = 0; fr < 5; ++fr) {
#pragma unroll
    for (int r = 0; r < 4; ++r) {
      const int grow = R0 + fr * 16 + lg * 4 + r;
      const int ownc = grow / 10;  // own speaker column
      float sm = 0.f;
#pragma unroll
      for (int fc = 0; fc < 2; ++fc) {
        const int gcol = C0 + fc * 16 + l15;
        float vv = wv * acc[fr][fc][r];
        if (gcol == ownc) vv = wv * simown[grow];
        sm += __expf(vv);
      }
#pragma unroll
      for (int off = 1; off < 16; off <<= 1) sm += __shfl_xor(sm, off, 16);
      if (l15 == 0) atomicAdd(&rowsum[grow], sm);
    }
  }
}

// ---------------------------------------------------------------------------
// Kernel C: loss_i = log(rowsum_i) - w*simown_i; sum over 10240 into d_out.
// ---------------------------------------------------------------------------
__global__ void __launch_bounds__(256) ge2e_final(
    const float* __restrict__ rowsum, const float* __restrict__ simown,
    const float* __restrict__ wp, float* __restrict__ out) {
  const int i = blockIdx.x * 256 + threadIdx.x;  // 0..10239
  const float wv = wp[0];
  float loss = logf(rowsum[i]) - wv * simown[i];
#pragma unroll
  for (int off = 32; off >= 1; off >>= 1) loss += __shfl_xor(loss, off);
  __shared__ float red[4];
  const int lane = threadIdx.x & 63, wid = threadIdx.x >> 6;
  if (lane == 0) red[wid] = loss;
  __syncthreads();
  if (threadIdx.x == 0) atomicAdd(out, red[0] + red[1] + red[2] + red[3]);
}

extern "C" void kernel_launch(void* const* d_in, const int* in_sizes, int n_in,
                              void* d_out, int out_size, void* d_ws, size_t ws_size,
                              hipStream_t stream) {
  (void)in_sizes; (void)n_in; (void)out_size; (void)ws_size;
  const float* dv = (const float*)d_in[0];
  const float* wp = (const float*)d_in[1];
  // d_in[2] (bias b) cancels exactly in -log_softmax[own]; unused.

  unsigned char* a8 = (unsigned char*)d_ws;                         // 7,864,320 B
  unsigned char* c8 = (unsigned char*)d_ws + 7864320;               //   786,432 B
  float* simown = (float*)((char*)d_ws + 8650752);                  //    40,960 B
  float* rowsum = (float*)((char*)d_ws + 8691712);                  //    40,960 B
  float* out = (float*)d_out;

  ge2e_pre<<<1024, 192, 0, stream>>>(dv, (unsigned int*)a8, (unsigned int*)c8,
                                     simown, rowsum, out);
  ge2e_gemm<<<512, 512, 0, stream>>>(a8, c8, simown, wp, rowsum);
  ge2e_final<<<40, 256, 0, stream>>>(rowsum, simown, wp, out);
}